// Round 1
// baseline (1034.079 us; speedup 1.0000x reference)
//
#include <hip/hip_runtime.h>
#include <math.h>

typedef unsigned short u16;
typedef unsigned int u32;
typedef float f32x4 __attribute__((ext_vector_type(4)));
typedef __bf16 bf16x8 __attribute__((ext_vector_type(8)));
typedef u16 us8 __attribute__((ext_vector_type(8)));
typedef u16 us4 __attribute__((ext_vector_type(4)));

#define MFMA_BF16 __builtin_amdgcn_mfma_f32_16x16x32_bf16

__device__ __forceinline__ u16 f2bf(float x){
  u32 u = __float_as_uint(x);
  u32 r = u + 0x7FFFu + ((u >> 16) & 1u);
  return (u16)(r >> 16);
}
__device__ __forceinline__ float bf2f(u16 h){ return __uint_as_float(((u32)h) << 16); }

// ---------------------------------------------------------------- split weights
__global__ __launch_bounds__(256) void k_split_w(const float* __restrict__ Wq,
                                                 const float* __restrict__ Wk,
                                                 const float* __restrict__ Wv,
                                                 u16* __restrict__ whi, u16* __restrict__ wlo){
  const int z = blockIdx.y;
  const float* W = (z == 0) ? Wq : (z == 1) ? Wk : Wv;
  u16* hi = whi + (size_t)z * 1048576u;
  u16* lo = wlo + (size_t)z * 1048576u;
  const int i = (blockIdx.x * 256 + threadIdx.x) * 4;
  f32x4 v = *(const f32x4*)(W + i);
  u16 h[4], l[4];
  #pragma unroll
  for (int j = 0; j < 4; j++){
    h[j] = f2bf(v[j]);
    l[j] = f2bf(v[j] - bf2f(h[j]));
  }
  *(us4*)&hi[i] = *(const us4*)&h[0];
  *(us4*)&lo[i] = *(const us4*)&l[0];
}

// ---------------------------------------------------------------- projection GEMM
// Q/K: 3-pass split bf16 (fp32-quality). V: 1-pass bf16.
__global__ __launch_bounds__(256) void k_proj(const float* __restrict__ H,
    const u16* __restrict__ Whi, const u16* __restrict__ Wlo,
    u16* __restrict__ Qhi, u16* __restrict__ Qlo,
    u16* __restrict__ Khi, u16* __restrict__ Klo,
    u16* __restrict__ Vhi)
{
  __shared__ __align__(16) u16 sAhi[128*40];
  __shared__ __align__(16) u16 sAlo[128*40];
  __shared__ __align__(16) u16 sBhi[128*40];
  __shared__ __align__(16) u16 sBlo[128*40];
  const int tid = threadIdx.x;
  const int z  = blockIdx.z;
  const int m0 = blockIdx.x * 128, n0 = blockIdx.y * 128;
  const u16* __restrict__ Wh = Whi + (size_t)z * 1048576u;
  const u16* __restrict__ Wl = Wlo + (size_t)z * 1048576u;

  const int wid = tid >> 6, lane = tid & 63;
  const int wr = wid >> 1, wc = wid & 1;
  const int lrow = lane & 15, lk = (lane >> 4) * 8;
  const int arow = tid >> 1, ahalf = tid & 1;
  const int grow = m0 + arow;
  const bool av = grow < 16400;
  const float* __restrict__ asrc = H + (size_t)grow * 1024;
  const size_t bgrow = (size_t)(n0 + arow) * 1024;

  f32x4 acc[4][4] = {};

  for (int k0 = 0; k0 < 1024; k0 += 32){
    const int co = k0 + ahalf * 16;
    { // stage A: f32 -> hi/lo bf16 split, in-register
      f32x4 x[4] = {{0,0,0,0},{0,0,0,0},{0,0,0,0},{0,0,0,0}};
      if (av){
        x[0] = *(const f32x4*)(asrc + co + 0);
        x[1] = *(const f32x4*)(asrc + co + 4);
        x[2] = *(const f32x4*)(asrc + co + 8);
        x[3] = *(const f32x4*)(asrc + co + 12);
      }
      u16 hi[16], lo[16];
      #pragma unroll
      for (int i = 0; i < 4; i++){
        #pragma unroll
        for (int j = 0; j < 4; j++){
          float f = x[i][j];
          u16 h = f2bf(f);
          hi[i*4+j] = h;
          lo[i*4+j] = f2bf(f - bf2f(h));
        }
      }
      *(us8*)&sAhi[arow*40 + ahalf*16 + 0] = *(const us8*)&hi[0];
      *(us8*)&sAhi[arow*40 + ahalf*16 + 8] = *(const us8*)&hi[8];
      *(us8*)&sAlo[arow*40 + ahalf*16 + 0] = *(const us8*)&lo[0];
      *(us8*)&sAlo[arow*40 + ahalf*16 + 8] = *(const us8*)&lo[8];
    }
    { // stage B from pre-split weights (rows n0+arow < 1024 always)
      *(us8*)&sBhi[arow*40 + ahalf*16 + 0] = *(const us8*)&Wh[bgrow + co + 0];
      *(us8*)&sBhi[arow*40 + ahalf*16 + 8] = *(const us8*)&Wh[bgrow + co + 8];
      *(us8*)&sBlo[arow*40 + ahalf*16 + 0] = *(const us8*)&Wl[bgrow + co + 0];
      *(us8*)&sBlo[arow*40 + ahalf*16 + 8] = *(const us8*)&Wl[bgrow + co + 8];
    }
    __syncthreads();
    bf16x8 ah[4], al[4], bh[4], bl[4];
    #pragma unroll
    for (int m = 0; m < 4; m++){
      ah[m] = *(const bf16x8*)&sAhi[(wr*64 + m*16 + lrow)*40 + lk];
      al[m] = *(const bf16x8*)&sAlo[(wr*64 + m*16 + lrow)*40 + lk];
    }
    #pragma unroll
    for (int n = 0; n < 4; n++){
      bh[n] = *(const bf16x8*)&sBhi[(wc*64 + n*16 + lrow)*40 + lk];
      bl[n] = *(const bf16x8*)&sBlo[(wc*64 + n*16 + lrow)*40 + lk];
    }
    #pragma unroll
    for (int m = 0; m < 4; m++){
      #pragma unroll
      for (int n = 0; n < 4; n++){
        acc[m][n] = MFMA_BF16(ah[m], bh[n], acc[m][n], 0, 0, 0);
        if (z != 2){
          acc[m][n] = MFMA_BF16(ah[m], bl[n], acc[m][n], 0, 0, 0);
          acc[m][n] = MFMA_BF16(al[m], bh[n], acc[m][n], 0, 0, 0);
        }
      }
    }
    __syncthreads();
  }
  const int r4 = (lane >> 4) * 4;
  #pragma unroll
  for (int m = 0; m < 4; m++){
    #pragma unroll
    for (int n = 0; n < 4; n++){
      #pragma unroll
      for (int j = 0; j < 4; j++){
        const int row = m0 + wr*64 + m*16 + r4 + j;
        const int col = n0 + wc*64 + n*16 + lrow;
        if (row < 16400){
          const float v = acc[m][n][j];
          const size_t o = (size_t)row * 1024 + col;
          if (z == 0){ u16 h = f2bf(v); Qhi[o] = h; Qlo[o] = f2bf(v - bf2f(h)); }
          else if (z == 1){ u16 h = f2bf(v); Khi[o] = h; Klo[o] = f2bf(v - bf2f(h)); }
          else { Vhi[o] = f2bf(v); }
        }
      }
    }
  }
}

// ---------------------------------------------------------------- scores GEMM (+bias)
__global__ __launch_bounds__(256) void k_scores(
    const u16* __restrict__ Qhi, const u16* __restrict__ Qlo,
    const u16* __restrict__ Khi, const u16* __restrict__ Klo,
    const float* __restrict__ bias_table, float* __restrict__ scores)
{
  __shared__ __align__(16) u16 sAhi[128*40];
  __shared__ __align__(16) u16 sAlo[128*40];
  __shared__ __align__(16) u16 sBhi[128*40];
  __shared__ __align__(16) u16 sBlo[128*40];
  const int tid = threadIdx.x;
  const int b  = blockIdx.z;
  const int m0 = blockIdx.x * 128, n0 = blockIdx.y * 128;
  const int wid = tid >> 6, lane = tid & 63;
  const int wr = wid >> 1, wc = wid & 1;
  const int lrow = lane & 15, lk = (lane >> 4) * 8;
  const int arow = tid >> 1, ahalf = tid & 1;
  const int qs = m0 + arow; const bool qv = qs < 1025;
  const int ks = n0 + arow; const bool kv = ks < 1025;
  const size_t qg = ((size_t)b * 1025 + qs) * 1024;
  const size_t kg = ((size_t)b * 1025 + ks) * 1024;
  const us8 z8 = {0,0,0,0,0,0,0,0};

  f32x4 acc[4][4] = {};

  for (int k0 = 0; k0 < 1024; k0 += 32){
    const int co = k0 + ahalf * 16;
    *(us8*)&sAhi[arow*40 + ahalf*16 + 0] = qv ? *(const us8*)&Qhi[qg + co + 0] : z8;
    *(us8*)&sAhi[arow*40 + ahalf*16 + 8] = qv ? *(const us8*)&Qhi[qg + co + 8] : z8;
    *(us8*)&sAlo[arow*40 + ahalf*16 + 0] = qv ? *(const us8*)&Qlo[qg + co + 0] : z8;
    *(us8*)&sAlo[arow*40 + ahalf*16 + 8] = qv ? *(const us8*)&Qlo[qg + co + 8] : z8;
    *(us8*)&sBhi[arow*40 + ahalf*16 + 0] = kv ? *(const us8*)&Khi[kg + co + 0] : z8;
    *(us8*)&sBhi[arow*40 + ahalf*16 + 8] = kv ? *(const us8*)&Khi[kg + co + 8] : z8;
    *(us8*)&sBlo[arow*40 + ahalf*16 + 0] = kv ? *(const us8*)&Klo[kg + co + 0] : z8;
    *(us8*)&sBlo[arow*40 + ahalf*16 + 8] = kv ? *(const us8*)&Klo[kg + co + 8] : z8;
    __syncthreads();
    bf16x8 ah[4], al[4], bh[4], bl[4];
    #pragma unroll
    for (int m = 0; m < 4; m++){
      ah[m] = *(const bf16x8*)&sAhi[(wr*64 + m*16 + lrow)*40 + lk];
      al[m] = *(const bf16x8*)&sAlo[(wr*64 + m*16 + lrow)*40 + lk];
    }
    #pragma unroll
    for (int n = 0; n < 4; n++){
      bh[n] = *(const bf16x8*)&sBhi[(wc*64 + n*16 + lrow)*40 + lk];
      bl[n] = *(const bf16x8*)&sBlo[(wc*64 + n*16 + lrow)*40 + lk];
    }
    #pragma unroll
    for (int m = 0; m < 4; m++){
      #pragma unroll
      for (int n = 0; n < 4; n++){
        acc[m][n] = MFMA_BF16(ah[m], bh[n], acc[m][n], 0, 0, 0);
        acc[m][n] = MFMA_BF16(ah[m], bl[n], acc[m][n], 0, 0, 0);
        acc[m][n] = MFMA_BF16(al[m], bh[n], acc[m][n], 0, 0, 0);
      }
    }
    __syncthreads();
  }
  const int r4 = (lane >> 4) * 4;
  #pragma unroll
  for (int m = 0; m < 4; m++){
    #pragma unroll
    for (int n = 0; n < 4; n++){
      #pragma unroll
      for (int j = 0; j < 4; j++){
        const int q  = m0 + wr*64 + m*16 + r4 + j;
        const int kk = n0 + wc*64 + n*16 + lrow;
        if (q < 1025 && kk < 1025){
          float v = acc[m][n][j];
          if (q > 0 && kk > 0){
            const int i = q - 1, jj = kk - 1;
            const int yi = i >> 5, xi = i & 31;
            const int yj = jj >> 5, xj = jj & 31;
            const int idx = (yi - yj + 31) * 63 + (xi - xj + 31);
            v += bias_table[idx * 16 + b];
          }
          scores[((size_t)b * 1025 + q) * 1028 + kk] = v;
        }
      }
    }
  }
}

// ---------------------------------------------------------------- V transpose
__global__ __launch_bounds__(256) void k_transpose_v(const u16* __restrict__ Vhi,
                                                     u16* __restrict__ Vt){
  __shared__ u16 T[32][33];
  const int b = blockIdx.z, s0 = blockIdx.x * 32, e0 = blockIdx.y * 32;
  const int tx = threadIdx.x & 31, ty = threadIdx.x >> 5;
  #pragma unroll
  for (int i = 0; i < 4; i++){
    const int s = s0 + ty + i * 8;
    T[ty + i*8][tx] = (s < 1025) ? Vhi[((size_t)b * 1025 + s) * 1024 + e0 + tx] : (u16)0;
  }
  __syncthreads();
  #pragma unroll
  for (int i = 0; i < 4; i++){
    const int e = e0 + ty + i * 8;
    const int s = s0 + tx;
    if (s < 1032) Vt[((size_t)b * 1024 + e) * 1032 + s] = T[tx][ty + i*8];
  }
}

// ---------------------------------------------------------------- softmax
__global__ __launch_bounds__(256) void k_softmax(const float* __restrict__ scores,
                                                 u16* __restrict__ P){
  __shared__ float red[4];
  const int tid = threadIdx.x;
  const size_t R = blockIdx.x;
  const float* __restrict__ row = scores + R * 1028;
  f32x4 v = *(const f32x4*)&row[tid * 4];
  const float extra = (tid == 0) ? row[1024] : -1e30f;
  float mx = fmaxf(fmaxf(v[0], v[1]), fmaxf(v[2], v[3]));
  mx = fmaxf(mx, extra);
  #pragma unroll
  for (int off = 32; off >= 1; off >>= 1) mx = fmaxf(mx, __shfl_down(mx, off, 64));
  if ((tid & 63) == 0) red[tid >> 6] = mx;
  __syncthreads();
  mx = fmaxf(fmaxf(red[0], red[1]), fmaxf(red[2], red[3]));
  __syncthreads();
  f32x4 e;
  e[0] = __expf(v[0] - mx); e[1] = __expf(v[1] - mx);
  e[2] = __expf(v[2] - mx); e[3] = __expf(v[3] - mx);
  const float e4 = (tid == 0) ? __expf(extra - mx) : 0.f;
  float s = e[0] + e[1] + e[2] + e[3] + e4;
  #pragma unroll
  for (int off = 32; off >= 1; off >>= 1) s += __shfl_down(s, off, 64);
  if ((tid & 63) == 0) red[tid >> 6] = s;
  __syncthreads();
  s = red[0] + red[1] + red[2] + red[3];
  const float inv = 1.0f / s;
  u16 p[4];
  p[0] = f2bf(e[0] * inv); p[1] = f2bf(e[1] * inv);
  p[2] = f2bf(e[2] * inv); p[3] = f2bf(e[3] * inv);
  *(us4*)&P[R * 1032 + tid * 4] = *(const us4*)&p[0];
  if (tid < 8){
    P[R * 1032 + 1024 + tid] = (tid == 0) ? f2bf(e4 * inv) : (u16)0;
  }
}

// ---------------------------------------------------------------- PV GEMM
__global__ __launch_bounds__(256) void k_pv(const u16* __restrict__ P,
                                            const u16* __restrict__ Vt,
                                            float* __restrict__ out)
{
  __shared__ __align__(16) u16 sA[128*40];
  __shared__ __align__(16) u16 sB[128*40];
  const int tid = threadIdx.x;
  const int b  = blockIdx.z;
  const int m0 = blockIdx.x * 128, n0 = blockIdx.y * 128;
  const int wid = tid >> 6, lane = tid & 63;
  const int wr = wid >> 1, wc = wid & 1;
  const int lrow = lane & 15, lk = (lane >> 4) * 8;
  const int arow = tid >> 1, ahalf = tid & 1;
  const int qs = m0 + arow; const bool qv = qs < 1025;
  const size_t pg = ((size_t)b * 1025 + qs) * 1032;
  const size_t vg = ((size_t)b * 1024 + n0 + arow) * 1032;
  const us8 z8 = {0,0,0,0,0,0,0,0};

  f32x4 acc[4][4] = {};

  for (int k0 = 0; k0 < 1056; k0 += 32){
    const int c0 = k0 + ahalf * 16;
    const bool v0 = (c0 + 8  <= 1032);
    const bool v1 = (c0 + 16 <= 1032);
    *(us8*)&sA[arow*40 + ahalf*16 + 0] = (qv && v0) ? *(const us8*)&P[pg + c0 + 0] : z8;
    *(us8*)&sA[arow*40 + ahalf*16 + 8] = (qv && v1) ? *(const us8*)&P[pg + c0 + 8] : z8;
    *(us8*)&sB[arow*40 + ahalf*16 + 0] = v0 ? *(const us8*)&Vt[vg + c0 + 0] : z8;
    *(us8*)&sB[arow*40 + ahalf*16 + 8] = v1 ? *(const us8*)&Vt[vg + c0 + 8] : z8;
    __syncthreads();
    bf16x8 a[4], bb[4];
    #pragma unroll
    for (int m = 0; m < 4; m++)
      a[m] = *(const bf16x8*)&sA[(wr*64 + m*16 + lrow)*40 + lk];
    #pragma unroll
    for (int n = 0; n < 4; n++)
      bb[n] = *(const bf16x8*)&sB[(wc*64 + n*16 + lrow)*40 + lk];
    #pragma unroll
    for (int m = 0; m < 4; m++){
      #pragma unroll
      for (int n = 0; n < 4; n++){
        acc[m][n] = MFMA_BF16(a[m], bb[n], acc[m][n], 0, 0, 0);
      }
    }
    __syncthreads();
  }
  const int r4 = (lane >> 4) * 4;
  #pragma unroll
  for (int m = 0; m < 4; m++){
    #pragma unroll
    for (int n = 0; n < 4; n++){
      #pragma unroll
      for (int j = 0; j < 4; j++){
        const int q = m0 + wr*64 + m*16 + r4 + j;
        const int e = n0 + wc*64 + n*16 + lrow;
        if (q < 1025){
          out[((size_t)b * 1025 + q) * 1024 + e] = acc[m][n][j];
        }
      }
    }
  }
}

// ---------------------------------------------------------------- launch
extern "C" void kernel_launch(void* const* d_in, const int* in_sizes, int n_in,
                              void* d_out, int out_size, void* d_ws, size_t ws_size,
                              hipStream_t stream)
{
  const float* H          = (const float*)d_in[0];
  const float* Wq         = (const float*)d_in[1];
  const float* Wk         = (const float*)d_in[2];
  const float* Wv         = (const float*)d_in[3];
  const float* bias_table = (const float*)d_in[4];
  float* out = (float*)d_out;
  char* ws = (char*)d_ws;

  // workspace layout (bytes). PLANE = 16400*1024*2 = 33,587,200
  const size_t PLANE = 33587200ull;
  u16* whi = (u16*)(ws + 0);                       //  6,291,456
  u16* wlo = (u16*)(ws + 6291456ull);              //  6,291,456
  u16* Qhi = (u16*)(ws + 12582912ull);
  u16* Qlo = (u16*)(ws + 12582912ull + PLANE);
  u16* Khi = (u16*)(ws + 12582912ull + 2*PLANE);
  u16* Klo = (u16*)(ws + 12582912ull + 3*PLANE);
  u16* Vhi = (u16*)(ws + 12582912ull + 4*PLANE);   // ends 180,518,912
  float* scores = (float*)(ws + 180518912ull);     // 67,436,800 -> ends 247,955,712
  // aliases (written only after k_scores has consumed Q/K/W):
  u16* Vt = (u16*)(ws + 46170112ull);              // over Qlo (+Khi head), 33,816,576
  u16* P  = (u16*)(ws + 0);                        // over whi/wlo/Qhi head, 33,849,600

  k_split_w   <<<dim3(1024, 3, 1),  256, 0, stream>>>(Wq, Wk, Wv, whi, wlo);
  k_proj      <<<dim3(129, 8, 3),   256, 0, stream>>>(H, whi, wlo, Qhi, Qlo, Khi, Klo, Vhi);
  k_scores    <<<dim3(9, 9, 16),    256, 0, stream>>>(Qhi, Qlo, Khi, Klo, bias_table, scores);
  k_transpose_v<<<dim3(33, 32, 16), 256, 0, stream>>>(Vhi, Vt);
  k_softmax   <<<dim3(16400, 1, 1), 256, 0, stream>>>(scores, P);
  k_pv        <<<dim3(9, 8, 16),    256, 0, stream>>>(P, Vt, out);
}

// Round 3
// 836.324 us; speedup vs baseline: 1.2365x; 1.2365x over previous
//
#include <hip/hip_runtime.h>
#include <math.h>

typedef unsigned short u16;
typedef unsigned int u32;
typedef float f32x4 __attribute__((ext_vector_type(4)));
typedef __bf16 bf16x8 __attribute__((ext_vector_type(8)));
typedef u16 us8 __attribute__((ext_vector_type(8)));
typedef u16 us4 __attribute__((ext_vector_type(4)));

#define MFMA_BF16 __builtin_amdgcn_mfma_f32_16x16x32_bf16

__device__ __forceinline__ u16 f2bf(float x){
  u32 u = __float_as_uint(x);
  u32 r = u + 0x7FFFu + ((u >> 16) & 1u);
  return (u16)(r >> 16);
}
__device__ __forceinline__ float bf2f(u16 h){ return __uint_as_float(((u32)h) << 16); }

// async global->LDS, 16B per lane; lds base must be wave-uniform (HW scatters lane*16)
__device__ __forceinline__ void gld16(u16* lds, const char* g){
  __builtin_amdgcn_global_load_lds((const __attribute__((address_space(1))) void*)g,
                                   (__attribute__((address_space(3))) void*)lds,
                                   16, 0, 0);
}

// ---------------------------------------------------------------- split weights
__global__ __launch_bounds__(256) void k_split_w(const float* __restrict__ Wq,
                                                 const float* __restrict__ Wk,
                                                 const float* __restrict__ Wv,
                                                 u16* __restrict__ whi, u16* __restrict__ wlo){
  const int z = blockIdx.y;
  const float* W = (z == 0) ? Wq : (z == 1) ? Wk : Wv;
  u16* hi = whi + (size_t)z * 1048576u;
  u16* lo = wlo + (size_t)z * 1048576u;
  const int i = (blockIdx.x * 256 + threadIdx.x) * 4;
  f32x4 v = *(const f32x4*)(W + i);
  u16 h[4], l[4];
  #pragma unroll
  for (int j = 0; j < 4; j++){
    h[j] = f2bf(v[j]);
    l[j] = f2bf(v[j] - bf2f(h[j]));
  }
  *(us4*)&hi[i] = *(const us4*)&h[0];
  *(us4*)&lo[i] = *(const us4*)&l[0];
}

// ---------------------------------------------------------------- split H
__global__ __launch_bounds__(256) void k_split_h(const float* __restrict__ H,
                                                 u16* __restrict__ Hhi, u16* __restrict__ Hlo){
  const size_t row = blockIdx.x;
  const int i = threadIdx.x * 4;
  f32x4 v = *(const f32x4*)(H + row * 1024 + i);
  u16 h[4], l[4];
  #pragma unroll
  for (int j = 0; j < 4; j++){
    h[j] = f2bf(v[j]);
    l[j] = f2bf(v[j] - bf2f(h[j]));
  }
  *(us4*)&Hhi[row * 1024 + i] = *(const us4*)&h[0];
  *(us4*)&Hlo[row * 1024 + i] = *(const us4*)&l[0];
}

// ---------------------------------------------------------------- projection GEMM
// Q/K: 3-pass split bf16 (fp32-quality). V: 1-pass bf16.
__global__ __launch_bounds__(256) void k_proj(
    const u16* __restrict__ Hhi, const u16* __restrict__ Hlo,
    const u16* __restrict__ Whi, const u16* __restrict__ Wlo,
    u16* __restrict__ Qhi, u16* __restrict__ Qlo,
    u16* __restrict__ Khi, u16* __restrict__ Klo,
    u16* __restrict__ Vhi)
{
  __shared__ __align__(16) u16 sAh[128*32];
  __shared__ __align__(16) u16 sAl[128*32];
  __shared__ __align__(16) u16 sBh[128*32];
  __shared__ __align__(16) u16 sBl[128*32];
  const int tid = threadIdx.x, lane = tid & 63, w = tid >> 6;
  const int z  = blockIdx.z;
  const int m0 = blockIdx.x * 128, n0 = blockIdx.y * 128;

  // staging source offsets (per-lane constants); tile row = 32w + (lane>>2) (+16 for chunk1)
  const int sr  = w * 32 + (lane >> 2);
  const int cb  = (lane & 3) * 16;
  const size_t aoff0 = (size_t)min(m0 + sr,      16399) * 2048 + cb;
  const size_t aoff1 = (size_t)min(m0 + sr + 16, 16399) * 2048 + cb;
  const size_t boff0 = (size_t)(n0 + sr)      * 2048 + cb;
  const size_t boff1 = (size_t)(n0 + sr + 16) * 2048 + cb;
  const char* Ah = (const char*)Hhi;
  const char* Al = (const char*)Hlo;
  const char* Bh = (const char*)(Whi + (size_t)z * 1048576u);
  const char* Bl = (const char*)(Wlo + (size_t)z * 1048576u);

  const int wr = w >> 1, wc = w & 1;
  const int lrow = lane & 15;
  const int fo = (lane >> 4) * 8;

  f32x4 acc[4][4] = {};

  for (int k0 = 0; k0 < 1024; k0 += 32){
    const size_t kb = (size_t)k0 * 2;
    gld16(sAh + w*1024,       Ah + aoff0 + kb);
    gld16(sAh + w*1024 + 512, Ah + aoff1 + kb);
    gld16(sBh + w*1024,       Bh + boff0 + kb);
    gld16(sBh + w*1024 + 512, Bh + boff1 + kb);
    if (z != 2){
      gld16(sAl + w*1024,       Al + aoff0 + kb);
      gld16(sAl + w*1024 + 512, Al + aoff1 + kb);
      gld16(sBl + w*1024,       Bl + boff0 + kb);
      gld16(sBl + w*1024 + 512, Bl + boff1 + kb);
    }
    __syncthreads();
    bf16x8 ah[4], bh[4];
    #pragma unroll
    for (int m = 0; m < 4; m++) ah[m] = *(const bf16x8*)&sAh[(wr*64 + m*16 + lrow)*32 + fo];
    #pragma unroll
    for (int n = 0; n < 4; n++) bh[n] = *(const bf16x8*)&sBh[(wc*64 + n*16 + lrow)*32 + fo];
    if (z != 2){
      bf16x8 al[4], bl[4];
      #pragma unroll
      for (int m = 0; m < 4; m++) al[m] = *(const bf16x8*)&sAl[(wr*64 + m*16 + lrow)*32 + fo];
      #pragma unroll
      for (int n = 0; n < 4; n++) bl[n] = *(const bf16x8*)&sBl[(wc*64 + n*16 + lrow)*32 + fo];
      #pragma unroll
      for (int m = 0; m < 4; m++){
        #pragma unroll
        for (int n = 0; n < 4; n++){
          acc[m][n] = MFMA_BF16(ah[m], bh[n], acc[m][n], 0, 0, 0);
          acc[m][n] = MFMA_BF16(ah[m], bl[n], acc[m][n], 0, 0, 0);
          acc[m][n] = MFMA_BF16(al[m], bh[n], acc[m][n], 0, 0, 0);
        }
      }
    } else {
      #pragma unroll
      for (int m = 0; m < 4; m++){
        #pragma unroll
        for (int n = 0; n < 4; n++){
          acc[m][n] = MFMA_BF16(ah[m], bh[n], acc[m][n], 0, 0, 0);
        }
      }
    }
    __syncthreads();
  }
  const int r4 = (lane >> 4) * 4;
  #pragma unroll
  for (int m = 0; m < 4; m++){
    #pragma unroll
    for (int n = 0; n < 4; n++){
      #pragma unroll
      for (int j = 0; j < 4; j++){
        const int row = m0 + wr*64 + m*16 + r4 + j;
        const int col = n0 + wc*64 + n*16 + lrow;
        if (row < 16400){
          const float v = acc[m][n][j];
          const size_t o = (size_t)row * 1024 + col;
          if (z == 0){ u16 h = f2bf(v); Qhi[o] = h; Qlo[o] = f2bf(v - bf2f(h)); }
          else if (z == 1){ u16 h = f2bf(v); Khi[o] = h; Klo[o] = f2bf(v - bf2f(h)); }
          else { Vhi[o] = f2bf(v); }
        }
      }
    }
  }
}

// ---------------------------------------------------------------- scores GEMM (+bias)
__global__ __launch_bounds__(256) void k_scores(
    const u16* __restrict__ Qhi, const u16* __restrict__ Qlo,
    const u16* __restrict__ Khi, const u16* __restrict__ Klo,
    const float* __restrict__ bias_table, float* __restrict__ scores)
{
  __shared__ __align__(16) u16 sAh[128*32];
  __shared__ __align__(16) u16 sAl[128*32];
  __shared__ __align__(16) u16 sBh[128*32];
  __shared__ __align__(16) u16 sBl[128*32];
  const int tid = threadIdx.x, lane = tid & 63, w = tid >> 6;
  const int b  = blockIdx.z;
  const int m0 = blockIdx.x * 128, n0 = blockIdx.y * 128;

  const int sr = w * 32 + (lane >> 2);
  const int cb = (lane & 3) * 16;
  const size_t aoff0 = ((size_t)b*1025 + min(m0 + sr,      1024)) * 2048 + cb;
  const size_t aoff1 = ((size_t)b*1025 + min(m0 + sr + 16, 1024)) * 2048 + cb;
  const size_t boff0 = ((size_t)b*1025 + min(n0 + sr,      1024)) * 2048 + cb;
  const size_t boff1 = ((size_t)b*1025 + min(n0 + sr + 16, 1024)) * 2048 + cb;
  const char* Ah = (const char*)Qhi;
  const char* Al = (const char*)Qlo;
  const char* Bh = (const char*)Khi;
  const char* Bl = (const char*)Klo;

  const int wr = w >> 1, wc = w & 1;
  const int lrow = lane & 15;
  const int fo = (lane >> 4) * 8;

  f32x4 acc[4][4] = {};

  for (int k0 = 0; k0 < 1024; k0 += 32){
    const size_t kb = (size_t)k0 * 2;
    gld16(sAh + w*1024,       Ah + aoff0 + kb);
    gld16(sAh + w*1024 + 512, Ah + aoff1 + kb);
    gld16(sAl + w*1024,       Al + aoff0 + kb);
    gld16(sAl + w*1024 + 512, Al + aoff1 + kb);
    gld16(sBh + w*1024,       Bh + boff0 + kb);
    gld16(sBh + w*1024 + 512, Bh + boff1 + kb);
    gld16(sBl + w*1024,       Bl + boff0 + kb);
    gld16(sBl + w*1024 + 512, Bl + boff1 + kb);
    __syncthreads();
    bf16x8 ah[4], al[4], bh[4], bl[4];
    #pragma unroll
    for (int m = 0; m < 4; m++){
      ah[m] = *(const bf16x8*)&sAh[(wr*64 + m*16 + lrow)*32 + fo];
      al[m] = *(const bf16x8*)&sAl[(wr*64 + m*16 + lrow)*32 + fo];
    }
    #pragma unroll
    for (int n = 0; n < 4; n++){
      bh[n] = *(const bf16x8*)&sBh[(wc*64 + n*16 + lrow)*32 + fo];
      bl[n] = *(const bf16x8*)&sBl[(wc*64 + n*16 + lrow)*32 + fo];
    }
    #pragma unroll
    for (int m = 0; m < 4; m++){
      #pragma unroll
      for (int n = 0; n < 4; n++){
        acc[m][n] = MFMA_BF16(ah[m], bh[n], acc[m][n], 0, 0, 0);
        acc[m][n] = MFMA_BF16(ah[m], bl[n], acc[m][n], 0, 0, 0);
        acc[m][n] = MFMA_BF16(al[m], bh[n], acc[m][n], 0, 0, 0);
      }
    }
    __syncthreads();
  }
  const int r4 = (lane >> 4) * 4;
  #pragma unroll
  for (int m = 0; m < 4; m++){
    #pragma unroll
    for (int n = 0; n < 4; n++){
      #pragma unroll
      for (int j = 0; j < 4; j++){
        const int q  = m0 + wr*64 + m*16 + r4 + j;
        const int kk = n0 + wc*64 + n*16 + lrow;
        if (q < 1025 && kk < 1025){
          float v = acc[m][n][j];
          if (q > 0 && kk > 0){
            const int i = q - 1, jj = kk - 1;
            const int yi = i >> 5, xi = i & 31;
            const int yj = jj >> 5, xj = jj & 31;
            const int idx = (yi - yj + 31) * 63 + (xi - xj + 31);
            v += bias_table[idx * 16 + b];
          }
          scores[((size_t)b * 1025 + q) * 1028 + kk] = v;
        }
      }
    }
  }
}

// ---------------------------------------------------------------- V transpose  (Vt stride 1056, pad cols zeroed)
__global__ __launch_bounds__(256) void k_transpose_v(const u16* __restrict__ Vhi,
                                                     u16* __restrict__ Vt){
  __shared__ u16 T[32][33];
  const int b = blockIdx.z, s0 = blockIdx.x * 32, e0 = blockIdx.y * 32;
  const int tx = threadIdx.x & 31, ty = threadIdx.x >> 5;
  #pragma unroll
  for (int i = 0; i < 4; i++){
    const int s = s0 + ty + i * 8;
    T[ty + i*8][tx] = (s < 1025) ? Vhi[((size_t)b * 1025 + s) * 1024 + e0 + tx] : (u16)0;
  }
  __syncthreads();
  #pragma unroll
  for (int i = 0; i < 4; i++){
    const int e = e0 + ty + i * 8;
    const int s = s0 + tx;
    Vt[((size_t)b * 1024 + e) * 1056 + s] = T[tx][ty + i*8];
  }
}

// ---------------------------------------------------------------- softmax  (P stride 1056, pad cols zeroed)
__global__ __launch_bounds__(256) void k_softmax(const float* __restrict__ scores,
                                                 u16* __restrict__ P){
  __shared__ float red[4];
  const int tid = threadIdx.x;
  const size_t R = blockIdx.x;
  const float* __restrict__ row = scores + R * 1028;
  f32x4 v = *(const f32x4*)&row[tid * 4];
  const float extra = (tid == 0) ? row[1024] : -1e30f;
  float mx = fmaxf(fmaxf(v[0], v[1]), fmaxf(v[2], v[3]));
  mx = fmaxf(mx, extra);
  #pragma unroll
  for (int off = 32; off >= 1; off >>= 1) mx = fmaxf(mx, __shfl_down(mx, off, 64));
  if ((tid & 63) == 0) red[tid >> 6] = mx;
  __syncthreads();
  mx = fmaxf(fmaxf(red[0], red[1]), fmaxf(red[2], red[3]));
  __syncthreads();
  f32x4 e;
  e[0] = __expf(v[0] - mx); e[1] = __expf(v[1] - mx);
  e[2] = __expf(v[2] - mx); e[3] = __expf(v[3] - mx);
  const float e4 = (tid == 0) ? __expf(extra - mx) : 0.f;
  float s = e[0] + e[1] + e[2] + e[3] + e4;
  #pragma unroll
  for (int off = 32; off >= 1; off >>= 1) s += __shfl_down(s, off, 64);
  if ((tid & 63) == 0) red[tid >> 6] = s;
  __syncthreads();
  s = red[0] + red[1] + red[2] + red[3];
  const float inv = 1.0f / s;
  u16 p[4];
  p[0] = f2bf(e[0] * inv); p[1] = f2bf(e[1] * inv);
  p[2] = f2bf(e[2] * inv); p[3] = f2bf(e[3] * inv);
  *(us4*)&P[R * 1056 + tid * 4] = *(const us4*)&p[0];
  if (tid < 32){
    P[R * 1056 + 1024 + tid] = (tid == 0) ? f2bf(e4 * inv) : (u16)0;
  }
}

// ---------------------------------------------------------------- PV GEMM
__global__ __launch_bounds__(256) void k_pv(const u16* __restrict__ P,
                                            const u16* __restrict__ Vt,
                                            float* __restrict__ out)
{
  __shared__ __align__(16) u16 sA[128*32];
  __shared__ __align__(16) u16 sB[128*32];
  const int tid = threadIdx.x, lane = tid & 63, w = tid >> 6;
  const int b  = blockIdx.z;
  const int m0 = blockIdx.x * 128, n0 = blockIdx.y * 128;

  const int sr = w * 32 + (lane >> 2);
  const int cb = (lane & 3) * 16;
  const size_t aoff0 = ((size_t)b*1025 + min(m0 + sr,      1024)) * 2112 + cb;
  const size_t aoff1 = ((size_t)b*1025 + min(m0 + sr + 16, 1024)) * 2112 + cb;
  const size_t boff0 = ((size_t)b*1024 + n0 + sr)      * 2112 + cb;
  const size_t boff1 = ((size_t)b*1024 + n0 + sr + 16) * 2112 + cb;
  const char* Ap = (const char*)P;
  const char* Bp = (const char*)Vt;

  const int wr = w >> 1, wc = w & 1;
  const int lrow = lane & 15;
  const int fo = (lane >> 4) * 8;

  f32x4 acc[4][4] = {};

  for (int k0 = 0; k0 < 1056; k0 += 32){
    const size_t kb = (size_t)k0 * 2;
    gld16(sA + w*1024,       Ap + aoff0 + kb);
    gld16(sA + w*1024 + 512, Ap + aoff1 + kb);
    gld16(sB + w*1024,       Bp + boff0 + kb);
    gld16(sB + w*1024 + 512, Bp + boff1 + kb);
    __syncthreads();
    bf16x8 a[4], bb[4];
    #pragma unroll
    for (int m = 0; m < 4; m++)
      a[m] = *(const bf16x8*)&sA[(wr*64 + m*16 + lrow)*32 + fo];
    #pragma unroll
    for (int n = 0; n < 4; n++)
      bb[n] = *(const bf16x8*)&sB[(wc*64 + n*16 + lrow)*32 + fo];
    #pragma unroll
    for (int m = 0; m < 4; m++){
      #pragma unroll
      for (int n = 0; n < 4; n++){
        acc[m][n] = MFMA_BF16(a[m], bb[n], acc[m][n], 0, 0, 0);
      }
    }
    __syncthreads();
  }
  const int r4 = (lane >> 4) * 4;
  #pragma unroll
  for (int m = 0; m < 4; m++){
    #pragma unroll
    for (int n = 0; n < 4; n++){
      #pragma unroll
      for (int j = 0; j < 4; j++){
        const int q = m0 + wr*64 + m*16 + r4 + j;
        const int e = n0 + wc*64 + n*16 + lrow;
        if (q < 1025){
          out[((size_t)b * 1025 + q) * 1024 + e] = acc[m][n][j];
        }
      }
    }
  }
}

// ---------------------------------------------------------------- launch
extern "C" void kernel_launch(void* const* d_in, const int* in_sizes, int n_in,
                              void* d_out, int out_size, void* d_ws, size_t ws_size,
                              hipStream_t stream)
{
  const float* H          = (const float*)d_in[0];
  const float* Wq         = (const float*)d_in[1];
  const float* Wk         = (const float*)d_in[2];
  const float* Wv         = (const float*)d_in[3];
  const float* bias_table = (const float*)d_in[4];
  float* out = (float*)d_out;
  char* ws = (char*)d_ws;

  // workspace layout (bytes), peak 247,955,712:
  //  [0,          33,587,200) Hhi            -> later scores [0, 67,436,800)
  //  [33,587,200, 67,174,400) Hlo
  //  [67,436,800, 73,728,256) Whi            -> later Vt [67,436,800, 102,039,808)
  //  [73,728,256, 80,019,712) Wlo
  //  [80,019,712,113,606,912) Qhi
  //  [113,606,912,147,194,112) Qlo           -> later P [113,606,912, 148,243,712)
  //  [147,194,112,180,781,312) Khi
  //  [180,781,312,214,368,512) Klo
  //  [214,368,512,247,955,712) Vhi
  u16* Hhi = (u16*)(ws + 0);
  u16* Hlo = (u16*)(ws + 33587200ull);
  u16* Whi = (u16*)(ws + 67436800ull);
  u16* Wlo = (u16*)(ws + 73728256ull);
  u16* Qhi = (u16*)(ws + 80019712ull);
  u16* Qlo = (u16*)(ws + 113606912ull);
  u16* Khi = (u16*)(ws + 147194112ull);
  u16* Klo = (u16*)(ws + 180781312ull);
  u16* Vhi = (u16*)(ws + 214368512ull);
  float* scores = (float*)(ws + 0);
  u16* Vt = (u16*)(ws + 67436800ull);
  u16* P  = (u16*)(ws + 113606912ull);

  k_split_w    <<<dim3(1024, 3, 1),  256, 0, stream>>>(Wq, Wk, Wv, Whi, Wlo);
  k_split_h    <<<dim3(16400, 1, 1), 256, 0, stream>>>(H, Hhi, Hlo);
  k_proj       <<<dim3(129, 8, 3),   256, 0, stream>>>(Hhi, Hlo, Whi, Wlo, Qhi, Qlo, Khi, Klo, Vhi);
  k_scores     <<<dim3(9, 9, 16),    256, 0, stream>>>(Qhi, Qlo, Khi, Klo, bias_table, scores);
  k_transpose_v<<<dim3(33, 32, 16),  256, 0, stream>>>(Vhi, Vt);
  k_softmax    <<<dim3(16400, 1, 1), 256, 0, stream>>>(scores, P);
  k_pv         <<<dim3(9, 8, 16),    256, 0, stream>>>(P, Vt, out);
}